// Round 1
// baseline (631.586 us; speedup 1.0000x reference)
//
#include <hip/hip_runtime.h>
#include <hip/hip_bf16.h>

#define N_ 8192
#define F_ 256
#define H_ 128
#define L_ 32

typedef __attribute__((ext_vector_type(8))) short bf16x8;
typedef __attribute__((ext_vector_type(4))) float f32x4;
typedef __attribute__((ext_vector_type(4))) short bf16x4;

// RNE float -> bf16 (finite inputs only; our data has no NaN/inf)
__device__ __forceinline__ unsigned f2bf_u(float x) {
    unsigned u = __builtin_bit_cast(unsigned, x);
    return (u + 0x7fffu + ((u >> 16) & 1u)) >> 16;
}
__device__ __forceinline__ short f2bf(float x) { return (short)f2bf_u(x); }

__device__ __forceinline__ bf16x8 cvt8(float4 a, float4 b) {
    bf16x8 v;
    v[0] = f2bf(a.x); v[1] = f2bf(a.y); v[2] = f2bf(a.z); v[3] = f2bf(a.w);
    v[4] = f2bf(b.x); v[5] = f2bf(b.y); v[6] = f2bf(b.z); v[7] = f2bf(b.w);
    return v;
}

// ---------------------------------------------------------------------------
// k1: XW1T[n][i] = (X @ W1)[i][n], bf16.  64 rows/block, 4 waves x 16 rows.
// ---------------------------------------------------------------------------
__global__ __launch_bounds__(256) void k1_xw1(const float* __restrict__ X,
                                              const float* __restrict__ W1,
                                              short* __restrict__ XW1T) {
    __shared__ short w1t[H_ * (F_ + 8)];   // [n][k], stride 264 (pad -> 2-way banks, free)
    const int tid = threadIdx.x;
    for (int idx = tid; idx < F_ * H_; idx += 256) {
        int k = idx >> 7, n = idx & 127;
        w1t[n * (F_ + 8) + k] = f2bf(W1[idx]);
    }
    __syncthreads();
    const int wv = tid >> 6, l = tid & 63;
    const int lm = l & 15, q = l >> 4;
    const int i0 = blockIdx.x * 64 + wv * 16;
    const float* xrow = X + (size_t)(i0 + lm) * F_;
    f32x4 acc[8];
#pragma unroll
    for (int j = 0; j < 8; ++j) acc[j] = (f32x4){0.f, 0.f, 0.f, 0.f};
#pragma unroll
    for (int k0 = 0; k0 < F_; k0 += 32) {
        float4 a0 = *(const float4*)(xrow + k0 + q * 8);
        float4 a1 = *(const float4*)(xrow + k0 + q * 8 + 4);
        bf16x8 af = cvt8(a0, a1);
#pragma unroll
        for (int j = 0; j < 8; ++j) {
            bf16x8 bf = *(const bf16x8*)&w1t[(j * 16 + lm) * (F_ + 8) + k0 + q * 8];
            acc[j] = __builtin_amdgcn_mfma_f32_16x16x32_bf16(af, bf, acc[j], 0, 0, 0);
        }
    }
    // C/D: col = lane&15 (= n), row = q*4+reg (= i). Transposed store is contiguous in i.
#pragma unroll
    for (int j = 0; j < 8; ++j) {
        bf16x4 o;
        o[0] = f2bf(acc[j][0]); o[1] = f2bf(acc[j][1]);
        o[2] = f2bf(acc[j][2]); o[3] = f2bf(acc[j][3]);
        *(bf16x4*)(XW1T + (size_t)(j * 16 + lm) * N_ + i0 + q * 4) = o;
    }
}

// ---------------------------------------------------------------------------
// k2: ZPT[j][i] = (relu(A @ XW1) @ W2)[i][j], bf16.
// 32 rows/block, 8 waves = 2 row-strips x 4 K-quarters. No LDS in hot loop.
// ---------------------------------------------------------------------------
__global__ __launch_bounds__(512) void k2_h_zp(const float* __restrict__ A,
                                               const short* __restrict__ XW1T,
                                               const float* __restrict__ W2,
                                               short* __restrict__ ZPT) {
    __shared__ float lacc[4][32][H_ + 4];     // K-quarter partials, 67.6 KB
    __shared__ short hl[32 * (H_ + 8)];       // relu(h) tile bf16
    __shared__ short w2t[L_ * (H_ + 8)];      // W2 transposed bf16
    const int tid = threadIdx.x;
    for (int idx = tid; idx < H_ * L_; idx += 512) {
        int k = idx >> 5, j = idx & 31;
        w2t[j * (H_ + 8) + k] = f2bf(W2[idx]);
    }
    const int wv = tid >> 6, l = tid & 63;
    const int lm = l & 15, q = l >> 4;
    const int s = wv & 1, kq = wv >> 1;
    const int i0 = blockIdx.x * 32;
    const float* arow = A + (size_t)(i0 + s * 16 + lm) * N_;
    f32x4 acc[8];
#pragma unroll
    for (int j = 0; j < 8; ++j) acc[j] = (f32x4){0.f, 0.f, 0.f, 0.f};
    const int kbeg = kq * (N_ / 4), kend = kbeg + N_ / 4;
#pragma unroll 4
    for (int k0 = kbeg; k0 < kend; k0 += 32) {
        float4 a0 = *(const float4*)(arow + k0 + q * 8);
        float4 a1 = *(const float4*)(arow + k0 + q * 8 + 4);
        bf16x8 af = cvt8(a0, a1);
#pragma unroll
        for (int j = 0; j < 8; ++j) {
            bf16x8 bf = *(const bf16x8*)(XW1T + (size_t)(j * 16 + lm) * N_ + k0 + q * 8);
            acc[j] = __builtin_amdgcn_mfma_f32_16x16x32_bf16(af, bf, acc[j], 0, 0, 0);
        }
    }
#pragma unroll
    for (int j = 0; j < 8; ++j)
#pragma unroll
        for (int r = 0; r < 4; ++r)
            lacc[kq][s * 16 + q * 4 + r][j * 16 + lm] = acc[j][r];
    __syncthreads();
    for (int e = tid; e < 32 * H_; e += 512) {
        int rr = e >> 7, c = e & 127;
        float v = (lacc[0][rr][c] + lacc[1][rr][c]) + (lacc[2][rr][c] + lacc[3][rr][c]);
        hl[rr * (H_ + 8) + c] = f2bf(v > 0.f ? v : 0.f);
    }
    __syncthreads();
    // epilogue: h(32x128) @ W2(128x32), waves 0..3 take one 16x16 tile each
    if (wv < 4) {
        const int ti = wv & 1, tj = wv >> 1;
        f32x4 a2 = (f32x4){0.f, 0.f, 0.f, 0.f};
#pragma unroll
        for (int k0 = 0; k0 < H_; k0 += 32) {
            bf16x8 af = *(const bf16x8*)&hl[(ti * 16 + lm) * (H_ + 8) + k0 + q * 8];
            bf16x8 bf = *(const bf16x8*)&w2t[(tj * 16 + lm) * (H_ + 8) + k0 + q * 8];
            a2 = __builtin_amdgcn_mfma_f32_16x16x32_bf16(af, bf, a2, 0, 0, 0);
        }
        bf16x4 o;
        o[0] = f2bf(a2[0]); o[1] = f2bf(a2[1]); o[2] = f2bf(a2[2]); o[3] = f2bf(a2[3]);
        *(bf16x4*)(ZPT + (size_t)(tj * 16 + lm) * N_ + i0 + ti * 16 + q * 4) = o;
    }
}

// ---------------------------------------------------------------------------
// k3: Z[i][j] = (A @ ZP)[i][j], bf16 row-major. Same skeleton as k2.
// ---------------------------------------------------------------------------
__global__ __launch_bounds__(512) void k3_z(const float* __restrict__ A,
                                            const short* __restrict__ ZPT,
                                            short* __restrict__ Z) {
    __shared__ float lacc[4][32][L_ + 4];   // 18.4 KB
    const int tid = threadIdx.x;
    const int wv = tid >> 6, l = tid & 63;
    const int lm = l & 15, q = l >> 4;
    const int s = wv & 1, kq = wv >> 1;
    const int i0 = blockIdx.x * 32;
    const float* arow = A + (size_t)(i0 + s * 16 + lm) * N_;
    f32x4 acc[2];
    acc[0] = (f32x4){0.f, 0.f, 0.f, 0.f};
    acc[1] = (f32x4){0.f, 0.f, 0.f, 0.f};
    const int kbeg = kq * (N_ / 4), kend = kbeg + N_ / 4;
#pragma unroll 4
    for (int k0 = kbeg; k0 < kend; k0 += 32) {
        float4 a0 = *(const float4*)(arow + k0 + q * 8);
        float4 a1 = *(const float4*)(arow + k0 + q * 8 + 4);
        bf16x8 af = cvt8(a0, a1);
#pragma unroll
        for (int j = 0; j < 2; ++j) {
            bf16x8 bf = *(const bf16x8*)(ZPT + (size_t)(j * 16 + lm) * N_ + k0 + q * 8);
            acc[j] = __builtin_amdgcn_mfma_f32_16x16x32_bf16(af, bf, acc[j], 0, 0, 0);
        }
    }
#pragma unroll
    for (int j = 0; j < 2; ++j)
#pragma unroll
        for (int r = 0; r < 4; ++r)
            lacc[kq][s * 16 + q * 4 + r][j * 16 + lm] = acc[j][r];
    __syncthreads();
    {   // 1024 outputs, 512 threads, 2 each -> one packed u32 store
        int e = tid * 2;
        int rr = e >> 5, c = e & 31;
        float v0 = (lacc[0][rr][c] + lacc[1][rr][c]) + (lacc[2][rr][c] + lacc[3][rr][c]);
        float v1 = (lacc[0][rr][c + 1] + lacc[1][rr][c + 1]) + (lacc[2][rr][c + 1] + lacc[3][rr][c + 1]);
        unsigned pk = f2bf_u(v0) | (f2bf_u(v1) << 16);
        *(unsigned*)(Z + (size_t)(i0 + rr) * L_ + c) = pk;
    }
}

// ---------------------------------------------------------------------------
// k4: out = sigmoid(Z @ Z^T). 128x128 tile/block, 4 waves x (32 x 128). K=32.
// ---------------------------------------------------------------------------
__global__ __launch_bounds__(256) void k4_dec(const short* __restrict__ Z,
                                              float* __restrict__ out) {
    const int tid = threadIdx.x;
    const int wv = tid >> 6, l = tid & 63;
    const int lm = l & 15, q = l >> 4;
    const int bj = blockIdx.x & 63, bi = blockIdx.x >> 6;
    const int i0 = bi * 128, j0 = bj * 128;
    bf16x8 af[2];
#pragma unroll
    for (int t = 0; t < 2; ++t)
        af[t] = *(const bf16x8*)(Z + (size_t)(i0 + wv * 32 + t * 16 + lm) * L_ + q * 8);
#pragma unroll
    for (int tj = 0; tj < 8; ++tj) {
        bf16x8 bf = *(const bf16x8*)(Z + (size_t)(j0 + tj * 16 + lm) * L_ + q * 8);
#pragma unroll
        for (int t = 0; t < 2; ++t) {
            f32x4 c = __builtin_amdgcn_mfma_f32_16x16x32_bf16(
                af[t], bf, (f32x4){0.f, 0.f, 0.f, 0.f}, 0, 0, 0);
            const int gi = i0 + wv * 32 + t * 16 + q * 4;
            float* op = out + (size_t)gi * N_ + j0 + tj * 16 + lm;
#pragma unroll
            for (int r = 0; r < 4; ++r) {
                float e = __expf(-c[r]);
                op[(size_t)r * N_] = __fdividef(1.f, 1.f + e);
            }
        }
    }
}

extern "C" void kernel_launch(void* const* d_in, const int* in_sizes, int n_in,
                              void* d_out, int out_size, void* d_ws, size_t ws_size,
                              hipStream_t stream) {
    const float* X  = (const float*)d_in[0];
    const float* A  = (const float*)d_in[1];
    const float* W1 = (const float*)d_in[2];
    const float* W2 = (const float*)d_in[3];
    float* out = (float*)d_out;

    short* XW1T = (short*)d_ws;            // [H][N] bf16, 2 MB
    short* ZPT  = XW1T + (size_t)H_ * N_;  // [L][N] bf16, 512 KB
    short* Z    = ZPT + (size_t)L_ * N_;   // [N][L] bf16, 512 KB

    k1_xw1<<<N_ / 64, 256, 0, stream>>>(X, W1, XW1T);
    k2_h_zp<<<N_ / 32, 512, 0, stream>>>(A, XW1T, W2, ZPT);
    k3_z<<<N_ / 32, 512, 0, stream>>>(A, ZPT, Z);
    k4_dec<<<(N_ / 128) * (N_ / 128), 256, 0, stream>>>(Z, out);
}

// Round 2
// 565.358 us; speedup vs baseline: 1.1171x; 1.1171x over previous
//
#include <hip/hip_runtime.h>
#include <hip/hip_bf16.h>

#define N_ 8192
#define F_ 256
#define H_ 128
#define L_ 32
#define BK 64

typedef __attribute__((ext_vector_type(8))) short bf16x8;
typedef __attribute__((ext_vector_type(4))) float f32x4;
typedef __attribute__((ext_vector_type(4))) short bf16x4;

// RNE float -> bf16 (finite inputs only)
__device__ __forceinline__ unsigned f2bf_u(float x) {
    unsigned u = __builtin_bit_cast(unsigned, x);
    return (u + 0x7fffu + ((u >> 16) & 1u)) >> 16;
}
__device__ __forceinline__ short f2bf(float x) { return (short)f2bf_u(x); }

__device__ __forceinline__ bf16x4 cvt4(float4 a) {
    bf16x4 v;
    v[0] = f2bf(a.x); v[1] = f2bf(a.y); v[2] = f2bf(a.z); v[3] = f2bf(a.w);
    return v;
}
__device__ __forceinline__ bf16x8 cvt8(float4 a, float4 b) {
    bf16x8 v;
    v[0] = f2bf(a.x); v[1] = f2bf(a.y); v[2] = f2bf(a.z); v[3] = f2bf(a.w);
    v[4] = f2bf(b.x); v[5] = f2bf(b.y); v[6] = f2bf(b.z); v[7] = f2bf(b.w);
    return v;
}

// ---------------------------------------------------------------------------
// k1: XW1T[n][i] = (X @ W1)[i][n], bf16.  64 rows/block, 4 waves x 16 rows.
// ---------------------------------------------------------------------------
__global__ __launch_bounds__(256) void k1_xw1(const float* __restrict__ X,
                                              const float* __restrict__ W1,
                                              short* __restrict__ XW1T) {
    __shared__ short w1t[H_ * (F_ + 8)];
    const int tid = threadIdx.x;
    for (int idx = tid; idx < F_ * H_; idx += 256) {
        int k = idx >> 7, n = idx & 127;
        w1t[n * (F_ + 8) + k] = f2bf(W1[idx]);
    }
    __syncthreads();
    const int wv = tid >> 6, l = tid & 63;
    const int lm = l & 15, q = l >> 4;
    const int i0 = blockIdx.x * 64 + wv * 16;
    const float* xrow = X + (size_t)(i0 + lm) * F_;
    f32x4 acc[8];
#pragma unroll
    for (int j = 0; j < 8; ++j) acc[j] = (f32x4){0.f, 0.f, 0.f, 0.f};
#pragma unroll
    for (int k0 = 0; k0 < F_; k0 += 32) {
        float4 a0 = *(const float4*)(xrow + k0 + q * 8);
        float4 a1 = *(const float4*)(xrow + k0 + q * 8 + 4);
        bf16x8 af = cvt8(a0, a1);
#pragma unroll
        for (int j = 0; j < 8; ++j) {
            bf16x8 bf = *(const bf16x8*)&w1t[(j * 16 + lm) * (F_ + 8) + k0 + q * 8];
            acc[j] = __builtin_amdgcn_mfma_f32_16x16x32_bf16(af, bf, acc[j], 0, 0, 0);
        }
    }
#pragma unroll
    for (int j = 0; j < 8; ++j) {
        bf16x4 o;
        o[0] = f2bf(acc[j][0]); o[1] = f2bf(acc[j][1]);
        o[2] = f2bf(acc[j][2]); o[3] = f2bf(acc[j][3]);
        *(bf16x4*)(XW1T + (size_t)(j * 16 + lm) * N_ + i0 + q * 4) = o;
    }
}

// ---------------------------------------------------------------------------
// k2: ZPT[j][i] = (relu(A @ XW1) @ W2)[i][j], bf16.
// 32 rows/block, 8 waves = 2 row-strips x 4 col-strips. Coalesced staged A/B,
// double-buffered LDS, prefetch distance 2, full-K accumulators in registers.
// ---------------------------------------------------------------------------
__global__ __launch_bounds__(512) void k2_h_zp(const float* __restrict__ A,
                                               const short* __restrict__ XW1T,
                                               const float* __restrict__ W2,
                                               short* __restrict__ ZPT) {
    __shared__ short As[2][32][72];     // 9.2 KB  (bf16 A tile, 2 bufs)
    __shared__ short Bs[2][128][72];    // 36.9 KB (bf16 B tile, 2 bufs)
    __shared__ short hl[32][136];       // 8.7 KB  relu(h)
    __shared__ short w2t[32][136];      // 8.7 KB  W2^T
    const int tid = threadIdx.x;
    for (int idx = tid; idx < H_ * L_; idx += 512) {
        int k = idx >> 5, j = idx & 31;
        w2t[j][k] = f2bf(W2[idx]);
    }
    const int wv = tid >> 6, l = tid & 63, lm = l & 15, q = l >> 4;
    const int rs = wv & 1, cs = wv >> 1;                // row strip / col strip
    const int i0 = blockIdx.x * 32;
    // staging coords: A 32x64 fp32 (wave = 4 rows x 256B contiguous),
    //                 B 128x64 bf16 (wave = 16 rows x 64B contiguous)
    const int ar = tid >> 4, ac = (tid & 15) * 4;
    const int br = tid >> 2, bc = (tid & 3) * 16;
    const float* Arow = A + (size_t)(i0 + ar) * N_ + ac;
    const short* Brow = XW1T + (size_t)br * N_ + bc;

    float4 pa[2]; bf16x8 pb0[2], pb1[2];
    pa[0]  = *(const float4*)(Arow);
    pb0[0] = *(const bf16x8*)(Brow);
    pb1[0] = *(const bf16x8*)(Brow + 8);
    pa[1]  = *(const float4*)(Arow + BK);
    pb0[1] = *(const bf16x8*)(Brow + BK);
    pb1[1] = *(const bf16x8*)(Brow + BK + 8);
    *(bf16x4*)&As[0][ar][ac] = cvt4(pa[0]);
    *(bf16x8*)&Bs[0][br][bc] = pb0[0];
    *(bf16x8*)&Bs[0][br][bc + 8] = pb1[0];
    pa[0]  = *(const float4*)(Arow + 2 * BK);
    pb0[0] = *(const bf16x8*)(Brow + 2 * BK);
    pb1[0] = *(const bf16x8*)(Brow + 2 * BK + 8);
    __syncthreads();

    f32x4 acc[2];
    acc[0] = (f32x4){0.f, 0.f, 0.f, 0.f};
    acc[1] = (f32x4){0.f, 0.f, 0.f, 0.f};
    const int NS = N_ / BK;   // 128
#pragma unroll 2
    for (int s = 0; s < NS; ++s) {
        const int buf = s & 1;
#pragma unroll
        for (int kh = 0; kh < 2; ++kh) {
            bf16x8 af = *(const bf16x8*)&As[buf][rs * 16 + lm][kh * 32 + q * 8];
#pragma unroll
            for (int jt = 0; jt < 2; ++jt) {
                bf16x8 bf = *(const bf16x8*)&Bs[buf][cs * 32 + jt * 16 + lm][kh * 32 + q * 8];
                acc[jt] = __builtin_amdgcn_mfma_f32_16x16x32_bf16(af, bf, acc[jt], 0, 0, 0);
            }
        }
        if (s + 1 < NS) {
            const int p = (s + 1) & 1;
            *(bf16x4*)&As[p][ar][ac] = cvt4(pa[p]);
            *(bf16x8*)&Bs[p][br][bc] = pb0[p];
            *(bf16x8*)&Bs[p][br][bc + 8] = pb1[p];
            if (s + 3 < NS) {
                pa[p]  = *(const float4*)(Arow + (s + 3) * BK);
                pb0[p] = *(const bf16x8*)(Brow + (s + 3) * BK);
                pb1[p] = *(const bf16x8*)(Brow + (s + 3) * BK + 8);
            }
        }
        __syncthreads();
    }
    // epilogue: relu -> hl, then h(32x128) @ W2(128x32)
#pragma unroll
    for (int jt = 0; jt < 2; ++jt)
#pragma unroll
        for (int r = 0; r < 4; ++r) {
            float v = acc[jt][r];
            hl[rs * 16 + q * 4 + r][cs * 32 + jt * 16 + lm] = f2bf(v > 0.f ? v : 0.f);
        }
    __syncthreads();
    if (wv < 4) {
        const int ti = wv & 1, tjw = wv >> 1;
        f32x4 a2 = (f32x4){0.f, 0.f, 0.f, 0.f};
#pragma unroll
        for (int k0 = 0; k0 < H_; k0 += 32) {
            bf16x8 af = *(const bf16x8*)&hl[ti * 16 + lm][k0 + q * 8];
            bf16x8 bf = *(const bf16x8*)&w2t[tjw * 16 + lm][k0 + q * 8];
            a2 = __builtin_amdgcn_mfma_f32_16x16x32_bf16(af, bf, a2, 0, 0, 0);
        }
        bf16x4 o;
        o[0] = f2bf(a2[0]); o[1] = f2bf(a2[1]); o[2] = f2bf(a2[2]); o[3] = f2bf(a2[3]);
        *(bf16x4*)(ZPT + (size_t)(tjw * 16 + lm) * N_ + i0 + ti * 16 + q * 4) = o;
    }
}

// ---------------------------------------------------------------------------
// k3: Z[i][j] = (A @ ZP)[i][j], bf16 row-major. Same staging skeleton,
// in-block K-split 2 (8 waves = 2 kq x 2 rs x 2 cs), LDS reduce at end.
// ---------------------------------------------------------------------------
__global__ __launch_bounds__(512) void k3_z(const float* __restrict__ A,
                                            const short* __restrict__ ZPT,
                                            short* __restrict__ Z) {
    __shared__ short As[2][2][32][72];   // [buf][kw][row][col]  18.4 KB
    __shared__ short Bs[2][2][32][72];   // 18.4 KB
    __shared__ float lacc[2][32][36];    // 9.2 KB
    const int tid = threadIdx.x;
    const int wv = tid >> 6, l = tid & 63, lm = l & 15, q = l >> 4;
    const int kq = wv >> 2, rs = (wv >> 1) & 1, cs = wv & 1;
    const int i0 = blockIdx.x * 32;
    // A staging: 2 windows x 32 rows x 64 fp32 -> thread does (row,c4) in both kw
    const int ar = (tid >> 4) & 31, ac = (tid & 15) * 4;
    // B staging: 2 windows x 32 rows x 64 bf16 -> kw = tid>>8
    const int bkw = tid >> 8, br = (tid >> 3) & 31, bc = (tid & 7) * 8;
    const float* Ar0 = A + (size_t)(i0 + ar) * N_ + ac;
    const float* Ar1 = Ar0 + N_ / 2;
    const short* Brow = ZPT + (size_t)br * N_ + bc + bkw * (N_ / 2);

    float4 pa0[2], pa1[2]; bf16x8 pb[2];
    pa0[0] = *(const float4*)(Ar0);
    pa1[0] = *(const float4*)(Ar1);
    pb[0]  = *(const bf16x8*)(Brow);
    pa0[1] = *(const float4*)(Ar0 + BK);
    pa1[1] = *(const float4*)(Ar1 + BK);
    pb[1]  = *(const bf16x8*)(Brow + BK);
    *(bf16x4*)&As[0][0][ar][ac] = cvt4(pa0[0]);
    *(bf16x4*)&As[0][1][ar][ac] = cvt4(pa1[0]);
    *(bf16x8*)&Bs[0][bkw][br][bc] = pb[0];
    pa0[0] = *(const float4*)(Ar0 + 2 * BK);
    pa1[0] = *(const float4*)(Ar1 + 2 * BK);
    pb[0]  = *(const bf16x8*)(Brow + 2 * BK);
    __syncthreads();

    f32x4 acc = (f32x4){0.f, 0.f, 0.f, 0.f};
    const int NS = (N_ / 2) / BK;   // 64
#pragma unroll 2
    for (int s = 0; s < NS; ++s) {
        const int buf = s & 1;
#pragma unroll
        for (int kh = 0; kh < 2; ++kh) {
            bf16x8 af = *(const bf16x8*)&As[buf][kq][rs * 16 + lm][kh * 32 + q * 8];
            bf16x8 bf = *(const bf16x8*)&Bs[buf][kq][cs * 16 + lm][kh * 32 + q * 8];
            acc = __builtin_amdgcn_mfma_f32_16x16x32_bf16(af, bf, acc, 0, 0, 0);
        }
        if (s + 1 < NS) {
            const int p = (s + 1) & 1;
            *(bf16x4*)&As[p][0][ar][ac] = cvt4(pa0[p]);
            *(bf16x4*)&As[p][1][ar][ac] = cvt4(pa1[p]);
            *(bf16x8*)&Bs[p][bkw][br][bc] = pb[p];
            if (s + 3 < NS) {
                pa0[p] = *(const float4*)(Ar0 + (s + 3) * BK);
                pa1[p] = *(const float4*)(Ar1 + (s + 3) * BK);
                pb[p]  = *(const bf16x8*)(Brow + (s + 3) * BK);
            }
        }
        __syncthreads();
    }
#pragma unroll
    for (int r = 0; r < 4; ++r)
        lacc[kq][rs * 16 + q * 4 + r][cs * 16 + lm] = acc[r];
    __syncthreads();
    {
        int e = tid * 2;
        int row = e >> 5, c = e & 31;
        float v0 = lacc[0][row][c] + lacc[1][row][c];
        float v1 = lacc[0][row][c + 1] + lacc[1][row][c + 1];
        unsigned pk = f2bf_u(v0) | (f2bf_u(v1) << 16);
        *(unsigned*)(Z + (size_t)(i0 + row) * L_ + c) = pk;
    }
}

// ---------------------------------------------------------------------------
// k4: out = sigmoid(Z @ Z^T). 128x128/block; sigmoid -> LDS -> coalesced
// float4 stores (1 KB/wave-instr).
// ---------------------------------------------------------------------------
__global__ __launch_bounds__(256) void k4_dec(const short* __restrict__ Z,
                                              float* __restrict__ out) {
    __shared__ float os[128][132];   // 67.6 KB -> 2 blocks/CU
    const int tid = threadIdx.x;
    const int wv = tid >> 6, l = tid & 63;
    const int lm = l & 15, q = l >> 4;
    const int bj = blockIdx.x & 63, bi = blockIdx.x >> 6;
    const int i0 = bi * 128, j0 = bj * 128;
    bf16x8 af[2];
#pragma unroll
    for (int t = 0; t < 2; ++t)
        af[t] = *(const bf16x8*)(Z + (size_t)(i0 + wv * 32 + t * 16 + lm) * L_ + q * 8);
#pragma unroll
    for (int tj = 0; tj < 8; ++tj) {
        bf16x8 bfv = *(const bf16x8*)(Z + (size_t)(j0 + tj * 16 + lm) * L_ + q * 8);
#pragma unroll
        for (int t = 0; t < 2; ++t) {
            f32x4 c = __builtin_amdgcn_mfma_f32_16x16x32_bf16(
                af[t], bfv, (f32x4){0.f, 0.f, 0.f, 0.f}, 0, 0, 0);
#pragma unroll
            for (int r = 0; r < 4; ++r) {
                float e = __expf(-c[r]);
                os[wv * 32 + t * 16 + q * 4 + r][tj * 16 + lm] = __fdividef(1.f, 1.f + e);
            }
        }
    }
    __syncthreads();
    for (int idx = tid; idx < 128 * 32; idx += 256) {
        int row = idx >> 5, c4 = idx & 31;
        *(float4*)(out + (size_t)(i0 + row) * N_ + j0 + c4 * 4) = *(const float4*)&os[row][c4 * 4];
    }
}

extern "C" void kernel_launch(void* const* d_in, const int* in_sizes, int n_in,
                              void* d_out, int out_size, void* d_ws, size_t ws_size,
                              hipStream_t stream) {
    const float* X  = (const float*)d_in[0];
    const float* A  = (const float*)d_in[1];
    const float* W1 = (const float*)d_in[2];
    const float* W2 = (const float*)d_in[3];
    float* out = (float*)d_out;

    short* XW1T = (short*)d_ws;            // [H][N] bf16, 2 MB
    short* ZPT  = XW1T + (size_t)H_ * N_;  // [L][N] bf16, 512 KB
    short* Z    = ZPT + (size_t)L_ * N_;   // [N][L] bf16, 512 KB

    k1_xw1<<<N_ / 64, 256, 0, stream>>>(X, W1, XW1T);
    k2_h_zp<<<N_ / 32, 512, 0, stream>>>(A, XW1T, W2, ZPT);
    k3_z<<<N_ / 32, 512, 0, stream>>>(A, ZPT, Z);
    k4_dec<<<(N_ / 128) * (N_ / 128), 256, 0, stream>>>(Z, out);
}